// Round 9
// baseline (30.332 us; speedup 1.0000x reference)
//
#include <hip/hip_runtime.h>
#include <math.h>

#define N_PIX   65536
#define NWL     112
#define NW      111          // columns 0..110 used
#define NATM    84
#define BLOCKS  2048
#define THREADS 256          // 4 waves/block
#define FTHREADS 1024        // finalize block size
#define ITERS   4            // 8 px per wave: 2048*4*8 = 65536 exactly

// K = WFA_CONSTANT * LAMBDA0^2 * G_FACTOR, rounded to f32 like the reference
#define KF ((float)(4.6686e-13 * 6301.5 * 6301.5 * 1.5))

// DPP ctrl encodings (gfx9/CDNA) — numerically verified rounds 3-8 (absmax 0.0)
#define DPP_QP_XOR1 0xB1    // quad_perm [1,0,3,2]
#define DPP_QP_XOR2 0x4E    // quad_perm [2,3,0,1]
#define DPP_ROR4    0x124   // row_ror:4
#define DPP_ROR8    0x128   // row_ror:8
#define DPP_BCAST15 0x142   // row_bcast15
#define DPP_WSHL1   0x130   // wave_shl:1
#define DPP_WSHR1   0x138   // wave_shr:1

template<int CTRL>
__device__ __forceinline__ float dpp_movf(float v) {
    return __int_as_float(__builtin_amdgcn_update_dpp(
        0, __float_as_int(v), CTRL, 0xF, 0xF, false));
}
template<int CTRL>
__device__ __forceinline__ float dpp_addf(float v) { return v + dpp_movf<CTRL>(v); }

// Sum across each 32-lane half; result valid in lanes 16..31 (half A) and
// 48..63 (half B). Lanes 32..47 polluted by bcast15 — never read there.
__device__ __forceinline__ float reduce_half32(float v) {
    v = dpp_addf<DPP_QP_XOR1>(v);
    v = dpp_addf<DPP_QP_XOR2>(v);
    v = dpp_addf<DPP_ROR4>(v);
    v = dpp_addf<DPP_ROR8>(v);
    v = dpp_addf<DPP_BCAST15>(v);
    return v;
}

__global__ __launch_bounds__(THREADS) void wfa_main(
    const float* __restrict__ stokes,   // (N_PIX, 4, 112)
    const float* __restrict__ pred,     // (N_PIX, 84)
    const float* __restrict__ targ,     // (N_PIX, 84)
    const float* __restrict__ wl,       // (112)
    double* __restrict__ partials)      // SoA: [0:B)=base, [B:2B)=cnt, [2B:3B)=wd
{
    const int tid  = threadIdx.x;
    const int lane = tid & 63;
    const int q    = lane & 31;          // position within half-wave
    const int hb   = (lane >> 5) & 1;    // 0 = pixel A half, 1 = pixel B half
    const bool ioL = q < 28;             // 28*4 = 112 floats of I/V

    // ---- loop-invariant: reciprocal of gradient(wl) (4 elements/lane) ----
    float rd0 = 0.f, rd1 = 0.f, rd2 = 0.f, rd3 = 0.f;
    {
        float4 w = make_float4(0.f, 0.f, 0.f, 0.f);
        if (ioL) w = *reinterpret_cast<const float4*>(wl + 4 * q);
        const float wprev = dpp_movf<DPP_WSHR1>(w.w);    // wl[4q-1]
        const float wnext = dpp_movf<DPP_WSHL1>(w.x);    // wl[4q+4]
        const float dwl0 = (q == 0)  ? (w.y - w.x) : 0.5f * (w.y - wprev);
        const float dwl1 = 0.5f * (w.z - w.x);
        const float dwl2 = (q == 27) ? (w.z - w.y) : 0.5f * (w.w - w.y); // j=110 edge
        const float dwl3 = (q == 27) ? 1.0f        : 0.5f * (wnext - w.z);
        if (ioL) { rd0 = 1.f/dwl0; rd1 = 1.f/dwl1; rd2 = 1.f/dwl2; rd3 = 1.f/dwl3; }
    }

    const int waveGlobal = blockIdx.x * (THREADS / 64) + (tid >> 6);
    const int pb         = waveGlobal * (2 * ITERS);   // pixels pb..pb+7

    double accBase = 0.0;  // all lanes
    double accCnt  = 0.0;  // lanes 16/48 only
    double accWd   = 0.0;  // lanes 16/48 only

    // ======== phase 1: DENSE pred/targ (8 px = 168 float4 each, 3 loads) ====
    float lp[8];   // log10(|pblos|+eps) per pixel, uniform across lanes
    {
        const float4* Pv = reinterpret_cast<const float4*>(pred) + (size_t)pb * 21;
        const float4* Tv = reinterpret_cast<const float4*>(targ) + (size_t)pb * 21;
        const float4 z = make_float4(0.f, 0.f, 0.f, 0.f);
        float4 PA = Pv[lane], PB = Pv[64 + lane], PC = z;
        float4 TA = Tv[lane], TB = Tv[64 + lane], TC = z;
        if (lane < 40) { PC = Pv[128 + lane]; TC = Tv[128 + lane]; }

        accBase += (double)(fabsf(PA.x-TA.x) + fabsf(PA.y-TA.y) +
                            fabsf(PA.z-TA.z) + fabsf(PA.w-TA.w));
        accBase += (double)(fabsf(PB.x-TB.x) + fabsf(PB.y-TB.y) +
                            fabsf(PB.z-TB.z) + fabsf(PB.w-TB.w));
        accBase += (double)(fabsf(PC.x-TC.x) + fabsf(PC.y-TC.y) +
                            fabsf(PC.z-TC.z) + fabsf(PC.w-TC.w));

        // pblos for pixel g: flat elems 3,7,11 = .w of float4 idx 21g+{0,1,2}
        const float paw = PA.w, pbw = PB.w, pcw = PC.w;
        #define LPX(a0, a1, a2) \
            log10f(fabsf(((a0) + (a1) + (a2)) / 3.0f) + 1e-10f)
        lp[0] = LPX(__shfl(paw, 0),  __shfl(paw, 1),  __shfl(paw, 2));
        lp[1] = LPX(__shfl(paw, 21), __shfl(paw, 22), __shfl(paw, 23));
        lp[2] = LPX(__shfl(paw, 42), __shfl(paw, 43), __shfl(paw, 44));
        lp[3] = LPX(__shfl(paw, 63), __shfl(pbw, 0),  __shfl(pbw, 1));
        lp[4] = LPX(__shfl(pbw, 20), __shfl(pbw, 21), __shfl(pbw, 22));
        lp[5] = LPX(__shfl(pbw, 41), __shfl(pbw, 42), __shfl(pbw, 43));
        lp[6] = LPX(__shfl(pbw, 62), __shfl(pbw, 63), __shfl(pcw, 0));
        lp[7] = LPX(__shfl(pcw, 19), __shfl(pcw, 20), __shfl(pcw, 21));
        #undef LPX
    }
    // Let P/T registers die before the I/V batch (occupancy guard).
    __builtin_amdgcn_sched_barrier(0);

    // ======== phase 2: WFA regression per pixel (I/V loads only) ===========
    float lw[4], mk[4];   // valid at lanes 16 (hb=0) / 48 (hb=1) per iteration
    #pragma unroll
    for (int it = 0; it < ITERS; ++it) {
        const int pix = pb + it * 2 + hb;
        const float* srow = stokes + (size_t)pix * (4 * NWL);

        float4 I4 = make_float4(0.f, 0.f, 0.f, 0.f);
        float4 V4 = make_float4(0.f, 0.f, 0.f, 0.f);
        if (ioL) {
            I4 = *reinterpret_cast<const float4*>(srow + 4 * q);
            V4 = *reinterpret_cast<const float4*>(srow + 3 * NWL + 4 * q);
        }

        // jnp.gradient(I): neighbors via DPP wave shifts (lane q holds j=4q..4q+3).
        // Cross-half leakage only reaches lanes whose value is unused
        // (q==0 uses edge formula; q==31 is inactive).
        const float iprev = dpp_movf<DPP_WSHR1>(I4.w);   // I[4q-1]
        const float inext = dpp_movf<DPP_WSHL1>(I4.x);   // I[4q+4]
        const float g0 = (q == 0)  ? (I4.y - I4.x) : 0.5f * (I4.y - iprev);
        const float g1 = 0.5f * (I4.z - I4.x);
        const float g2 = (q == 27) ? (I4.z - I4.y) : 0.5f * (I4.w - I4.y);
        const float g3 = 0.5f * (inext - I4.z);
        float d0 = g0 * rd0, d1 = g1 * rd1, d2 = g2 * rd2, d3 = g3 * rd3;
        float vx = V4.x, vy = V4.y, vz = V4.z, vw = V4.w;
        if (q == 27) { d3 = 0.f; vw = 0.f; }            // j=111 excluded
        if (!ioL)    { d0 = d1 = d2 = d3 = 0.f; }

        float sdI = d0 + d1 + d2 + d3;
        float sV  = vx + vy + vz + vw;
        float sdd = d0*d0 + d1*d1 + d2*d2 + d3*d3;
        float sdv = d0*vx + d1*vy + d2*vz + d3*vw;

        sdI = reduce_half32(sdI);
        sV  = reduce_half32(sV);
        sdd = reduce_half32(sdd);
        sdv = reduce_half32(sdv);

        lw[it] = 0.f; mk[it] = 0.f;
        if (q == 16) {   // reduce_half32 results valid here (lanes 16 / 48)
            const float nf   = (float)NW;
            const float coef = (nf * sdv - sdI * sV) / (nf * sdd - sdI * sdI);
            const float wfa  = -coef / KF;
            mk[it] = (fabsf(wfa) < 1.0e6f) ? 1.0f : 0.0f;
            lw[it] = log10f(fabsf(wfa) + 1e-10f);
        }
    }

    // ======== phase 3: combine (register-only) ==============================
    // Pixel g = it*2 + hb handled by lane 16 + 32*hb with lw[it]/mk[it].
    #pragma unroll
    for (int g = 0; g < 8; ++g) {
        const int it  = g >> 1;
        const int tgt = 16 + 32 * (g & 1);
        if (lane == tgt) {
            accCnt += (double)mk[it];
            accWd  += (double)(mk[it] * fabsf(lp[g] - lw[it]));
        }
    }

    // ---- block reduction (LDS tree, barriers only here) ----
    __shared__ double sB[THREADS], sC[THREADS], sW[THREADS];
    sB[tid] = accBase; sC[tid] = accCnt; sW[tid] = accWd;
    __syncthreads();
    #pragma unroll
    for (int s = 128; s; s >>= 1) {
        if (tid < s) {
            sB[tid] += sB[tid + s];
            sC[tid] += sC[tid + s];
            sW[tid] += sW[tid + s];
        }
        __syncthreads();
    }
    if (tid == 0) {
        partials[blockIdx.x             ] = sB[0];
        partials[blockIdx.x +     BLOCKS] = sC[0];
        partials[blockIdx.x + 2 * BLOCKS] = sW[0];
    }
}

__global__ __launch_bounds__(FTHREADS) void wfa_final(
    const double* __restrict__ partials, float* __restrict__ out)
{
    __shared__ double sB[FTHREADS], sC[FTHREADS], sW[FTHREADS];
    const int tid = threadIdx.x;

    double b = 0.0, c = 0.0, w = 0.0;
    for (int i = tid; i < BLOCKS / 2; i += FTHREADS) {
        const double2 b2 = reinterpret_cast<const double2*>(partials             )[i];
        const double2 c2 = reinterpret_cast<const double2*>(partials +     BLOCKS)[i];
        const double2 w2 = reinterpret_cast<const double2*>(partials + 2 * BLOCKS)[i];
        b += b2.x + b2.y;
        c += c2.x + c2.y;
        w += w2.x + w2.y;
    }
    sB[tid] = b; sC[tid] = c; sW[tid] = w;
    __syncthreads();
    #pragma unroll
    for (int s = FTHREADS / 2; s; s >>= 1) {
        if (tid < s) {
            sB[tid] += sB[tid + s];
            sC[tid] += sC[tid + s];
            sW[tid] += sW[tid + s];
        }
        __syncthreads();
    }
    if (tid == 0) {
        const double base     = sB[0] / ((double)N_PIX * (double)NATM);
        const double cnt      = sC[0];
        const double wfa_mean = sW[0] / fmax(cnt, 1.0);
        const bool   apply    = (base < 10.0) && (cnt > 0.0);
        const double wfa_loss = apply ? wfa_mean : 0.0;
        const double total    = apply ? (0.5 * base + 0.5 * wfa_mean) : base;
        out[0] = (float)total;
        out[1] = (float)base;
        out[2] = (float)wfa_loss;
    }
}

extern "C" void kernel_launch(void* const* d_in, const int* in_sizes, int n_in,
                              void* d_out, int out_size, void* d_ws, size_t ws_size,
                              hipStream_t stream) {
    (void)in_sizes; (void)n_in; (void)out_size; (void)ws_size;

    const float* stokes = (const float*)d_in[0];
    const float* pred   = (const float*)d_in[1];
    const float* targ   = (const float*)d_in[2];
    const float* wl     = (const float*)d_in[3];
    float* out          = (float*)d_out;
    double* partials    = (double*)d_ws;

    wfa_main<<<BLOCKS, THREADS, 0, stream>>>(stokes, pred, targ, wl, partials);
    wfa_final<<<1, FTHREADS, 0, stream>>>(partials, out);
}

// Round 10
// 27.216 us; speedup vs baseline: 1.1145x; 1.1145x over previous
//
#include <hip/hip_runtime.h>
#include <math.h>

#define N_PIX   65536
#define NWL     112
#define NW      111          // columns 0..110 used
#define NATM    84
#define BLOCKS  2048
#define THREADS 256          // 4 waves/block
#define FTHREADS 1024        // finalize block size
#define ITERS   4            // 2048 blk * 4 waves * 2 px * 4 it = 65536 exactly

// K = WFA_CONSTANT * LAMBDA0^2 * G_FACTOR, rounded to f32 like the reference
#define KF ((float)(4.6686e-13 * 6301.5 * 6301.5 * 1.5))

// DPP ctrl encodings (gfx9/CDNA) — numerically verified rounds 3-9 (absmax 0.0)
#define DPP_QP_XOR1 0xB1    // quad_perm [1,0,3,2]
#define DPP_QP_XOR2 0x4E    // quad_perm [2,3,0,1]
#define DPP_ROR4    0x124   // row_ror:4
#define DPP_ROR8    0x128   // row_ror:8
#define DPP_BCAST15 0x142   // row_bcast15
#define DPP_WSHL1   0x130   // wave_shl:1
#define DPP_WSHR1   0x138   // wave_shr:1

template<int CTRL>
__device__ __forceinline__ float dpp_movf(float v) {
    return __int_as_float(__builtin_amdgcn_update_dpp(
        0, __float_as_int(v), CTRL, 0xF, 0xF, false));
}
template<int CTRL>
__device__ __forceinline__ float dpp_addf(float v) { return v + dpp_movf<CTRL>(v); }

// Sum across each 32-lane half; result valid in lanes 16..31 (half A) and
// 48..63 (half B). Lanes 32..47 polluted by bcast15 — never read there.
__device__ __forceinline__ float reduce_half32(float v) {
    v = dpp_addf<DPP_QP_XOR1>(v);
    v = dpp_addf<DPP_QP_XOR2>(v);
    v = dpp_addf<DPP_ROR4>(v);
    v = dpp_addf<DPP_ROR8>(v);
    v = dpp_addf<DPP_BCAST15>(v);
    return v;
}

__global__ __launch_bounds__(THREADS) void wfa_main(
    const float* __restrict__ stokes,   // (N_PIX, 4, 112)
    const float* __restrict__ pred,     // (N_PIX, 84)
    const float* __restrict__ targ,     // (N_PIX, 84)
    const float* __restrict__ wl,       // (112)
    double* __restrict__ partials)      // SoA: [0:B)=base, [B:2B)=cnt, [2B:3B)=wd
{
    const int tid  = threadIdx.x;
    const int lane = tid & 63;
    const int q    = lane & 31;          // position within half-wave
    const int hb   = (lane >> 5) & 1;    // 0 = pixel A half, 1 = pixel B half
    const bool ioL = q < 28;             // 28*4 = 112 floats of I/V
    const bool pL  = q < 21;             // 21*4 = 84 floats of pred/targ

    // ---- loop-invariant: reciprocal of gradient(wl) (4 elements/lane) ----
    float rd0 = 0.f, rd1 = 0.f, rd2 = 0.f, rd3 = 0.f;
    {
        float4 w = make_float4(0.f, 0.f, 0.f, 0.f);
        if (ioL) w = *reinterpret_cast<const float4*>(wl + 4 * q);
        const float wprev = dpp_movf<DPP_WSHR1>(w.w);    // wl[4q-1]
        const float wnext = dpp_movf<DPP_WSHL1>(w.x);    // wl[4q+4]
        const float dwl0 = (q == 0)  ? (w.y - w.x) : 0.5f * (w.y - wprev);
        const float dwl1 = 0.5f * (w.z - w.x);
        const float dwl2 = (q == 27) ? (w.z - w.y) : 0.5f * (w.w - w.y); // j=110 edge
        const float dwl3 = (q == 27) ? 1.0f        : 0.5f * (wnext - w.z);
        if (ioL) { rd0 = 1.f/dwl0; rd1 = 1.f/dwl1; rd2 = 1.f/dwl2; rd3 = 1.f/dwl3; }
    }

    const int waveGlobal = blockIdx.x * (THREADS / 64) + (tid >> 6);

    double accBase = 0.0;  // all lanes
    double accCnt  = 0.0;  // q==16 lanes only
    double accWd   = 0.0;  // q==16 lanes only

    #pragma unroll
    for (int it = 0; it < ITERS; ++it) {
        const int pix = waveGlobal * (2 * ITERS) + it * 2 + hb;
        const float* srow = stokes + (size_t)pix * (4 * NWL);

        float4 I4 = make_float4(0.f, 0.f, 0.f, 0.f);
        float4 V4 = make_float4(0.f, 0.f, 0.f, 0.f);
        float4 P4 = make_float4(0.f, 0.f, 0.f, 0.f);
        float4 T4 = make_float4(0.f, 0.f, 0.f, 0.f);
        if (ioL) {
            I4 = *reinterpret_cast<const float4*>(srow + 4 * q);
            V4 = *reinterpret_cast<const float4*>(srow + 3 * NWL + 4 * q);
        }
        if (pL) {
            P4 = *reinterpret_cast<const float4*>(pred + (size_t)pix * NATM + 4 * q);
            T4 = *reinterpret_cast<const float4*>(targ + (size_t)pix * NATM + 4 * q);
        }

        // jnp.gradient(I): neighbors via DPP wave shifts (lane q holds j=4q..4q+3).
        // Cross-half leakage only reaches lanes whose value is unused
        // (q==0 uses edge formula; q==31 is inactive).
        const float iprev = dpp_movf<DPP_WSHR1>(I4.w);   // I[4q-1]
        const float inext = dpp_movf<DPP_WSHL1>(I4.x);   // I[4q+4]
        const float g0 = (q == 0)  ? (I4.y - I4.x) : 0.5f * (I4.y - iprev);
        const float g1 = 0.5f * (I4.z - I4.x);
        const float g2 = (q == 27) ? (I4.z - I4.y) : 0.5f * (I4.w - I4.y);
        const float g3 = 0.5f * (inext - I4.z);
        float d0 = g0 * rd0, d1 = g1 * rd1, d2 = g2 * rd2, d3 = g3 * rd3;
        float vx = V4.x, vy = V4.y, vz = V4.z, vw = V4.w;
        if (q == 27) { d3 = 0.f; vw = 0.f; }            // j=111 excluded
        if (!ioL)    { d0 = d1 = d2 = d3 = 0.f; }

        float sdI = d0 + d1 + d2 + d3;
        float sV  = vx + vy + vz + vw;
        float sdd = d0*d0 + d1*d1 + d2*d2 + d3*d3;
        float sdv = d0*vx + d1*vy + d2*vz + d3*vw;
        // predicted_blos contributions: flat elems 3,7,11 = P4.w of q==0,1,2
        float ps  = (q < 3) ? P4.w : 0.f;

        sdI = reduce_half32(sdI);
        sV  = reduce_half32(sV);
        sdd = reduce_half32(sdd);
        sdv = reduce_half32(sdv);
        ps  = reduce_half32(ps);

        // base-loss partial (inactive lanes contribute exact zeros)
        accBase += (double)(fabsf(P4.x - T4.x) + fabsf(P4.y - T4.y) +
                            fabsf(P4.z - T4.z) + fabsf(P4.w - T4.w));

        if (q == 16) {   // reduce_half32 results valid here (lanes 16 / 48)
            const float pblos = ps / 3.0f;
            const float nf    = (float)NW;
            const float coef  = (nf * sdv - sdI * sV) / (nf * sdd - sdI * sdI);
            const float wfa   = -coef / KF;
            const float mask  = (fabsf(wfa) < 1.0e6f) ? 1.0f : 0.0f;
            const float lp    = log10f(fabsf(pblos) + 1e-10f);
            const float lw    = log10f(fabsf(wfa)   + 1e-10f);
            accCnt += (double)mask;
            accWd  += (double)(mask * fabsf(lp - lw));
        }
    }

    // ---- block reduction (LDS tree, barriers only here) ----
    __shared__ double sB[THREADS], sC[THREADS], sW[THREADS];
    sB[tid] = accBase; sC[tid] = accCnt; sW[tid] = accWd;
    __syncthreads();
    #pragma unroll
    for (int s = 128; s; s >>= 1) {
        if (tid < s) {
            sB[tid] += sB[tid + s];
            sC[tid] += sC[tid + s];
            sW[tid] += sW[tid + s];
        }
        __syncthreads();
    }
    if (tid == 0) {
        partials[blockIdx.x             ] = sB[0];
        partials[blockIdx.x +     BLOCKS] = sC[0];
        partials[blockIdx.x + 2 * BLOCKS] = sW[0];
    }
}

__global__ __launch_bounds__(FTHREADS) void wfa_final(
    const double* __restrict__ partials, float* __restrict__ out)
{
    __shared__ double sB[FTHREADS], sC[FTHREADS], sW[FTHREADS];
    const int tid = threadIdx.x;

    // SoA layout lets each thread read one double2 per array (aligned:
    // partials base is d_ws, BLOCKS is even).
    double b = 0.0, c = 0.0, w = 0.0;
    for (int i = tid; i < BLOCKS / 2; i += FTHREADS) {
        const double2 b2 = reinterpret_cast<const double2*>(partials             )[i];
        const double2 c2 = reinterpret_cast<const double2*>(partials +     BLOCKS)[i];
        const double2 w2 = reinterpret_cast<const double2*>(partials + 2 * BLOCKS)[i];
        b += b2.x + b2.y;
        c += c2.x + c2.y;
        w += w2.x + w2.y;
    }
    sB[tid] = b; sC[tid] = c; sW[tid] = w;
    __syncthreads();
    #pragma unroll
    for (int s = FTHREADS / 2; s; s >>= 1) {
        if (tid < s) {
            sB[tid] += sB[tid + s];
            sC[tid] += sC[tid + s];
            sW[tid] += sW[tid + s];
        }
        __syncthreads();
    }
    if (tid == 0) {
        const double base     = sB[0] / ((double)N_PIX * (double)NATM);
        const double cnt      = sC[0];
        const double wfa_mean = sW[0] / fmax(cnt, 1.0);
        const bool   apply    = (base < 10.0) && (cnt > 0.0);
        const double wfa_loss = apply ? wfa_mean : 0.0;
        const double total    = apply ? (0.5 * base + 0.5 * wfa_mean) : base;
        out[0] = (float)total;
        out[1] = (float)base;
        out[2] = (float)wfa_loss;
    }
}

extern "C" void kernel_launch(void* const* d_in, const int* in_sizes, int n_in,
                              void* d_out, int out_size, void* d_ws, size_t ws_size,
                              hipStream_t stream) {
    (void)in_sizes; (void)n_in; (void)out_size; (void)ws_size;

    const float* stokes = (const float*)d_in[0];
    const float* pred   = (const float*)d_in[1];
    const float* targ   = (const float*)d_in[2];
    const float* wl     = (const float*)d_in[3];
    float* out          = (float*)d_out;
    double* partials    = (double*)d_ws;

    wfa_main<<<BLOCKS, THREADS, 0, stream>>>(stokes, pred, targ, wl, partials);
    wfa_final<<<1, FTHREADS, 0, stream>>>(partials, out);
}